// Round 5
// baseline (734.440 us; speedup 1.0000x reference)
//
#include <hip/hip_runtime.h>
#include <hip/hip_bf16.h>

#define N_TOK 16384
#define DIM   128
#define JT     64      // K/V tile (j) per iteration

#define KP 136         // kbuf row stride (shorts): 128 + 8 pad
#define VP 72          // vbuf row stride: 64 + 8 pad
#define PP 72          // pbuf row stride: 64 + 8 pad

using bf16x8 = __attribute__((ext_vector_type(8))) short;   // 8 bf16 = 4 VGPRs (MFMA A/B frag)
using f32x4  = __attribute__((ext_vector_type(4))) float;   // MFMA C/D frag

static __device__ __forceinline__ unsigned short f2b(float f) {
    union { __hip_bfloat16 h; unsigned short u; } cv;
    cv.h = __float2bfloat16(f);   // RNE
    return cv.u;
}

// Load 8 consecutive fp32, round to bf16, pack as MFMA fragment half.
static __device__ __forceinline__ bf16x8 load8f(const float* p) {
    float4 a = *reinterpret_cast<const float4*>(p);
    float4 b = *reinterpret_cast<const float4*>(p + 4);
    bf16x8 r;
    r[0] = (short)f2b(a.x); r[1] = (short)f2b(a.y);
    r[2] = (short)f2b(a.z); r[3] = (short)f2b(a.w);
    r[4] = (short)f2b(b.x); r[5] = (short)f2b(b.y);
    r[6] = (short)f2b(b.z); r[7] = (short)f2b(b.w);
    return r;
}

// ---------------------------------------------------------------------------
// Marker: fill out with a diagnostic constant (host-side guard failures).
// ---------------------------------------------------------------------------
__global__ __launch_bounds__(256)
void marker_kernel(float* out, float val)
{
    int i = blockIdx.x * 256 + threadIdx.x;
    if (i < N_TOK * DIM) out[i] = val;
}

// ---------------------------------------------------------------------------
// QKV: Q = x@Wq^T, K = x@Wk^T, Vt = (x@Wv^T)^T.  fp32 in, bf16 out (ws).
// grid (N/64, 3), block 256. Wave handles 16 rows x 128 cols.
// MFMA 16x16x32 bf16: A[m=lane&15][k=quad*8+j], B[n=lane&15][k=quad*8+j],
// C/D: col=lane&15, row=quad*4+reg (m89-verified).
// ---------------------------------------------------------------------------
__global__ __launch_bounds__(256)
void qkv_kernel(const float* __restrict__ x,
                const float* __restrict__ wq,
                const float* __restrict__ wk,
                const float* __restrict__ wv,
                unsigned short* __restrict__ Q,
                unsigned short* __restrict__ K,
                unsigned short* __restrict__ Vt)
{
    const int t = threadIdx.x;
    const int wave = t >> 6, lane = t & 63;
    const int ln = lane & 15, quad = lane >> 4, q8 = quad * 8;
    const int z = blockIdx.y;
    const float* W = (z == 0) ? wq : (z == 1) ? wk : wv;
    const int r0 = blockIdx.x * 64 + wave * 16;

    bf16x8 a[4];
#pragma unroll
    for (int ks = 0; ks < 4; ++ks)
        a[ks] = load8f(&x[(size_t)(r0 + ln) * DIM + ks * 32 + q8]);

    f32x4 acc[8];
#pragma unroll
    for (int nt = 0; nt < 8; ++nt) acc[nt] = f32x4{0.f, 0.f, 0.f, 0.f};

#pragma unroll
    for (int nt = 0; nt < 8; ++nt)
#pragma unroll
        for (int ks = 0; ks < 4; ++ks) {
            bf16x8 b = load8f(&W[(size_t)(nt * 16 + ln) * DIM + ks * 32 + q8]);
            acc[nt] = __builtin_amdgcn_mfma_f32_16x16x32_bf16(a[ks], b, acc[nt], 0, 0, 0);
        }

#pragma unroll
    for (int nt = 0; nt < 8; ++nt) {
        const int col = nt * 16 + ln;
        if (z == 2) {
            // V transposed: Vt[d=col][n=row]; 4 consecutive rows -> one 8B store
            ushort4 v4;
            v4.x = f2b(acc[nt][0]); v4.y = f2b(acc[nt][1]);
            v4.z = f2b(acc[nt][2]); v4.w = f2b(acc[nt][3]);
            *reinterpret_cast<ushort4*>(&Vt[(size_t)col * N_TOK + r0 + quad * 4]) = v4;
        } else {
            unsigned short* dst = (z == 0) ? Q : K;
#pragma unroll
            for (int r = 0; r < 4; ++r)
                dst[(size_t)(r0 + quad * 4 + r) * DIM + col] = f2b(acc[nt][r]);
        }
    }
}

// ---------------------------------------------------------------------------
// Flash attention, direct path: 4 waves x 16 rows = 64 Q-rows per block,
// grid N/64 = 256. Log2-domain online softmax; same-user bias fused.
// Output fp32 (reference dtype). uid physical layout (int64 vs int32)
// sniffed wave-uniformly from data (values < 512 => int64 odd words all 0).
// Canaries: NaN -> 12345, bad softmax denominator -> 23456.
// ---------------------------------------------------------------------------
__global__ __launch_bounds__(256, 2)
void flash_kernel(const unsigned short* __restrict__ Q,
                  const unsigned short* __restrict__ K,
                  const unsigned short* __restrict__ Vt,
                  const unsigned int* __restrict__ u32,
                  float* __restrict__ out)
{
    __shared__ unsigned short kbuf[JT][KP];
    __shared__ unsigned short vbuf[DIM][VP];
    __shared__ unsigned short pbuf[4][16][PP];
    __shared__ int ubuf[JT];

    const int t = threadIdx.x;
    const int wave = t >> 6, lane = t & 63;
    const int ln = lane & 15, quad = lane >> 4, q8 = quad * 8;
    const int r0 = blockIdx.x * 64 + wave * 16;

    const float lscale = 1.4426950408889634f * 0.08838834764831845f; // log2(e)/sqrt(128)
    const float bias2  = 5.0f * 1.4426950408889634f;                 // 5*log2(e)
    const float NEGBIG = -1.0e30f;

    // uid dtype sniff: identical verdict on every thread (uniform branch)
    bool i64 = true;
    for (int k = 0; k < 64; ++k) i64 = i64 && (u32[2 * k + 1] == 0u);

    bf16x8 qf[4];
    int uq[4];
#pragma unroll
    for (int ks = 0; ks < 4; ++ks)
        qf[ks] = *reinterpret_cast<const bf16x8*>(&Q[(size_t)(r0 + ln) * DIM + ks * 32 + q8]);
#pragma unroll
    for (int r = 0; r < 4; ++r) {
        int i = r0 + quad * 4 + r;
        uq[r] = (int)(i64 ? u32[2 * i] : u32[i]);
    }

    f32x4 o[8];
#pragma unroll
    for (int dt = 0; dt < 8; ++dt) o[dt] = f32x4{0.f, 0.f, 0.f, 0.f};
    float mrun[4], lrun[4];
#pragma unroll
    for (int r = 0; r < 4; ++r) { mrun[r] = NEGBIG; lrun[r] = 0.f; }

    unsigned short* pw = &pbuf[wave][0][0];

    for (int j = 0; j < N_TOK; j += JT) {
        // ---- stage K tile (64x128) and Vt tile (128x64), 16B per lane ----
#pragma unroll
        for (int p = 0; p < 4; ++p) {
            int slot = p * 256 + t;
            int row = slot >> 4, seg = slot & 15;
            *reinterpret_cast<uint4*>(&kbuf[row][seg * 8]) =
                *reinterpret_cast<const uint4*>(&K[(size_t)(j + row) * DIM + seg * 8]);
        }
#pragma unroll
        for (int p = 0; p < 4; ++p) {
            int slot = p * 256 + t;
            int row = slot >> 3, seg = slot & 7;
            *reinterpret_cast<uint4*>(&vbuf[row][seg * 8]) =
                *reinterpret_cast<const uint4*>(&Vt[(size_t)row * N_TOK + j + seg * 8]);
        }
        if (t < JT) {
            int i = j + t;
            ubuf[t] = (int)(i64 ? u32[2 * i] : u32[i]);
        }
        __syncthreads();

        // ---- S = Q @ K^T (16 rows x 64 cols per wave) ----
        f32x4 s[4];
#pragma unroll
        for (int nt = 0; nt < 4; ++nt) s[nt] = f32x4{0.f, 0.f, 0.f, 0.f};
#pragma unroll
        for (int nt = 0; nt < 4; ++nt)
#pragma unroll
            for (int ks = 0; ks < 4; ++ks) {
                bf16x8 b = *reinterpret_cast<const bf16x8*>(&kbuf[nt * 16 + ln][ks * 32 + q8]);
                s[nt] = __builtin_amdgcn_mfma_f32_16x16x32_bf16(qf[ks], b, s[nt], 0, 0, 0);
            }

        int uk[4];
#pragma unroll
        for (int nt = 0; nt < 4; ++nt) uk[nt] = ubuf[nt * 16 + ln];

        // ---- online softmax (log2 domain); row m = quad*4+r held by 16 lanes ----
#pragma unroll
        for (int r = 0; r < 4; ++r) {
            float lm = NEGBIG;
#pragma unroll
            for (int nt = 0; nt < 4; ++nt) {
                float v = s[nt][r] * lscale + (uq[r] == uk[nt] ? bias2 : 0.0f);
                s[nt][r] = v;
                lm = fmaxf(lm, v);
            }
            lm = fmaxf(lm, __shfl_xor(lm, 1, 64));
            lm = fmaxf(lm, __shfl_xor(lm, 2, 64));
            lm = fmaxf(lm, __shfl_xor(lm, 4, 64));
            lm = fmaxf(lm, __shfl_xor(lm, 8, 64));
            float mold = mrun[r];
            float mnew = fmaxf(mold, lm);
            float alpha = exp2f(mold - mnew);   // ~0 on first tile
            mrun[r] = mnew;
            float rs = 0.f;
#pragma unroll
            for (int nt = 0; nt < 4; ++nt) {
                float p = exp2f(s[nt][r] - mnew);
                s[nt][r] = p;
                rs += p;
            }
            rs += __shfl_xor(rs, 1, 64);
            rs += __shfl_xor(rs, 2, 64);
            rs += __shfl_xor(rs, 4, 64);
            rs += __shfl_xor(rs, 8, 64);
            lrun[r] = lrun[r] * alpha + rs;
#pragma unroll
            for (int dt = 0; dt < 8; ++dt) o[dt][r] *= alpha;
            // P (C-layout) -> LDS for A-layout reload
#pragma unroll
            for (int nt = 0; nt < 4; ++nt)
                pw[(quad * 4 + r) * PP + nt * 16 + ln] = f2b(s[nt][r]);
        }

        __syncthreads();   // P writes visible before fragment reads (and kbuf reads done)

        // ---- O += P @ V ----
        bf16x8 pa[2];
#pragma unroll
        for (int k2 = 0; k2 < 2; ++k2)
            pa[k2] = *reinterpret_cast<const bf16x8*>(&pw[ln * PP + k2 * 32 + q8]);
#pragma unroll
        for (int dt = 0; dt < 8; ++dt)
#pragma unroll
            for (int k2 = 0; k2 < 2; ++k2) {
                bf16x8 b = *reinterpret_cast<const bf16x8*>(&vbuf[dt * 16 + ln][k2 * 32 + q8]);
                o[dt] = __builtin_amdgcn_mfma_f32_16x16x32_bf16(pa[k2], b, o[dt], 0, 0, 0);
            }
        __syncthreads();   // protect kbuf/vbuf/pbuf before next staging
    }

    // ---- epilogue: normalize, canary, store fp32 ----
#pragma unroll
    for (int r = 0; r < 4; ++r) {
        float l = lrun[r];
        bool lbad = !(l > 0.f) || !(l < 3.0e38f);
        float inv = 1.0f / l;
        int row = r0 + quad * 4 + r;
#pragma unroll
        for (int dt = 0; dt < 8; ++dt) {
            float v = o[dt][r] * inv;
            if (v != v) v = 12345.0f;        // NaN canary
            if (lbad)   v = 23456.0f;        // bad denominator canary
            out[(size_t)row * DIM + dt * 16 + ln] = v;
        }
    }
}

// ---------------------------------------------------------------------------
extern "C" void kernel_launch(void* const* d_in, const int* in_sizes, int n_in,
                              void* d_out, int out_size, void* d_ws, size_t ws_size,
                              hipStream_t stream)
{
    float* out = (float*)d_out;

    // Shape sanity: signature 5555 if the problem isn't what we assume.
    bool ok = (n_in == 5) &&
              in_sizes[0] == N_TOK * DIM && in_sizes[1] == N_TOK &&
              in_sizes[2] == DIM * DIM && in_sizes[3] == DIM * DIM &&
              in_sizes[4] == DIM * DIM && out_size == N_TOK * DIM;
    if (!ok) { marker_kernel<<<8192, 256, 0, stream>>>(out, 5555.f); return; }

    const float*        xf  = (const float*)d_in[0];
    const unsigned int* u32 = (const unsigned int*)d_in[1];
    const float*        wqf = (const float*)d_in[2];
    const float*        wkf = (const float*)d_in[3];
    const float*        wvf = (const float*)d_in[4];

    char* ws = (char*)d_ws;
    size_t off = 0;
    unsigned short* Q  = (unsigned short*)(ws + off); off += (size_t)N_TOK * DIM * 2;  // 4 MB
    unsigned short* K  = (unsigned short*)(ws + off); off += (size_t)N_TOK * DIM * 2;  // 4 MB
    unsigned short* Vt = (unsigned short*)(ws + off); off += (size_t)N_TOK * DIM * 2;  // 4 MB

    // Workspace sanity: signature 4444 if ws can't hold Q/K/Vt.
    if (ws_size < off) { marker_kernel<<<8192, 256, 0, stream>>>(out, 4444.f); return; }

    qkv_kernel<<<dim3(N_TOK / 64, 3), 256, 0, stream>>>(xf, wqf, wkf, wvf, Q, K, Vt);
    flash_kernel<<<N_TOK / 64, 256, 0, stream>>>(Q, K, Vt, u32, out);
}

// Round 6
// 321.825 us; speedup vs baseline: 2.2821x; 2.2821x over previous
//
#include <hip/hip_runtime.h>
#include <hip/hip_bf16.h>

#define N_TOK 16384
#define DIM   128
#define JT     64      // K/V tile (j) per iteration

#define KP 136         // kbuf row stride (shorts): 128 + 8 pad
#define VP 72          // vbuf row stride: 64 + 8 pad
#define PP 80          // pbuf row stride (shorts): 64 + 16 pad -> quad stride 40 dwords = 8 banks: conflict-free b16 writes

using bf16x8 = __attribute__((ext_vector_type(8))) short;   // 8 bf16 = 4 VGPRs (MFMA A/B frag)
using f32x4  = __attribute__((ext_vector_type(4))) float;   // MFMA C/D frag

static __device__ __forceinline__ unsigned short f2b(float f) {
    union { __hip_bfloat16 h; unsigned short u; } cv;
    cv.h = __float2bfloat16(f);   // RNE
    return cv.u;
}

// Load 8 consecutive fp32, round to bf16, pack as MFMA fragment half.
static __device__ __forceinline__ bf16x8 load8f(const float* p) {
    float4 a = *reinterpret_cast<const float4*>(p);
    float4 b = *reinterpret_cast<const float4*>(p + 4);
    bf16x8 r;
    r[0] = (short)f2b(a.x); r[1] = (short)f2b(a.y);
    r[2] = (short)f2b(a.z); r[3] = (short)f2b(a.w);
    r[4] = (short)f2b(b.x); r[5] = (short)f2b(b.y);
    r[6] = (short)f2b(b.z); r[7] = (short)f2b(b.w);
    return r;
}

// ---------------------------------------------------------------------------
// Marker: fill out with a diagnostic constant (host-side guard failures).
// ---------------------------------------------------------------------------
__global__ __launch_bounds__(256)
void marker_kernel(float* out, float val)
{
    int i = blockIdx.x * 256 + threadIdx.x;
    if (i < N_TOK * DIM) out[i] = val;
}

// ---------------------------------------------------------------------------
// QKV: Q = x@Wq^T, K = x@Wk^T, Vt = (x@Wv^T)^T.  fp32 in, bf16 out (ws).
// grid (N/64, 3), block 256. Wave handles 16 rows x 128 cols.
// MFMA 16x16x32 bf16: A[m=lane&15][k=quad*8+j], B[n=lane&15][k=quad*8+j],
// C/D: col=lane&15, row=quad*4+reg (m89-verified).
// ---------------------------------------------------------------------------
__global__ __launch_bounds__(256)
void qkv_kernel(const float* __restrict__ x,
                const float* __restrict__ wq,
                const float* __restrict__ wk,
                const float* __restrict__ wv,
                unsigned short* __restrict__ Q,
                unsigned short* __restrict__ K,
                unsigned short* __restrict__ Vt)
{
    const int t = threadIdx.x;
    const int wave = t >> 6, lane = t & 63;
    const int ln = lane & 15, quad = lane >> 4, q8 = quad * 8;
    const int z = blockIdx.y;
    const float* W = (z == 0) ? wq : (z == 1) ? wk : wv;
    const int r0 = blockIdx.x * 64 + wave * 16;

    bf16x8 a[4];
#pragma unroll
    for (int ks = 0; ks < 4; ++ks)
        a[ks] = load8f(&x[(size_t)(r0 + ln) * DIM + ks * 32 + q8]);

    f32x4 acc[8];
#pragma unroll
    for (int nt = 0; nt < 8; ++nt) acc[nt] = f32x4{0.f, 0.f, 0.f, 0.f};

#pragma unroll
    for (int nt = 0; nt < 8; ++nt)
#pragma unroll
        for (int ks = 0; ks < 4; ++ks) {
            bf16x8 b = load8f(&W[(size_t)(nt * 16 + ln) * DIM + ks * 32 + q8]);
            acc[nt] = __builtin_amdgcn_mfma_f32_16x16x32_bf16(a[ks], b, acc[nt], 0, 0, 0);
        }

#pragma unroll
    for (int nt = 0; nt < 8; ++nt) {
        const int col = nt * 16 + ln;
        if (z == 2) {
            // V transposed: Vt[d=col][n=row]; 4 consecutive rows -> one 8B store
            ushort4 v4;
            v4.x = f2b(acc[nt][0]); v4.y = f2b(acc[nt][1]);
            v4.z = f2b(acc[nt][2]); v4.w = f2b(acc[nt][3]);
            *reinterpret_cast<ushort4*>(&Vt[(size_t)col * N_TOK + r0 + quad * 4]) = v4;
        } else {
            unsigned short* dst = (z == 0) ? Q : K;
#pragma unroll
            for (int r = 0; r < 4; ++r)
                dst[(size_t)(r0 + quad * 4 + r) * DIM + col] = f2b(acc[nt][r]);
        }
    }
}

// ---------------------------------------------------------------------------
// Flash attention, fixed-offset softmax (exact: p = exp2(logit*log2e - 16),
// O = sum p*V, l = sum p, out = O/l; no running max needed since logits are
// bounded and fp32/bf16 are scale-invariant over the occurring range).
// MT=2: 4 waves x 32 rows = 128 Q-rows/block. grid (N/128, nsplit).
// Split mode (out==nullptr): write partial O (fp32) and partial l; merging
// is a plain sum across splits. Direct mode: normalize and write fp32 out.
// ---------------------------------------------------------------------------
__global__ __launch_bounds__(256, 2)
void flash_kernel(const unsigned short* __restrict__ Q,
                  const unsigned short* __restrict__ K,
                  const unsigned short* __restrict__ Vt,
                  const unsigned int* __restrict__ u32,
                  int jspan,
                  float* __restrict__ pO, float* __restrict__ pl,
                  float* __restrict__ out)
{
    __shared__ unsigned short kbuf[JT][KP];
    __shared__ unsigned short vbuf[DIM][VP];
    __shared__ unsigned short pbuf[4][32][PP];
    __shared__ int ubuf[JT];

    const int t = threadIdx.x;
    const int wave = t >> 6, lane = t & 63;
    const int ln = lane & 15, quad = lane >> 4, q8 = quad * 8;
    const int r0 = blockIdx.x * 128 + wave * 32;
    const int split = blockIdx.y;
    const int j0 = split * jspan;
    const int j1 = j0 + jspan;

    const float lscale = 1.4426950408889634f * 0.08838834764831845f; // log2(e)/sqrt(128)
    const float cbias  = 5.0f * 1.4426950408889634f - 16.0f;         // same-user: 5*log2e - 16
    const float cnob   = -16.0f;                                     // different user

    // uid dtype sniff: identical verdict on every thread (uniform branch)
    bool i64 = true;
    for (int k = 0; k < 64; ++k) i64 = i64 && (u32[2 * k + 1] == 0u);

    bf16x8 qf[2][4];
    int uq[2][4];
#pragma unroll
    for (int mt = 0; mt < 2; ++mt) {
#pragma unroll
        for (int ks = 0; ks < 4; ++ks)
            qf[mt][ks] = *reinterpret_cast<const bf16x8*>(
                &Q[(size_t)(r0 + mt * 16 + ln) * DIM + ks * 32 + q8]);
#pragma unroll
        for (int r = 0; r < 4; ++r) {
            int i = r0 + mt * 16 + quad * 4 + r;
            uq[mt][r] = (int)(i64 ? u32[2 * i] : u32[i]);
        }
    }

    f32x4 o[2][8];
#pragma unroll
    for (int mt = 0; mt < 2; ++mt)
#pragma unroll
        for (int dt = 0; dt < 8; ++dt) o[mt][dt] = f32x4{0.f, 0.f, 0.f, 0.f};
    float lsum[2][4];
#pragma unroll
    for (int mt = 0; mt < 2; ++mt)
#pragma unroll
        for (int r = 0; r < 4; ++r) lsum[mt][r] = 0.f;

    unsigned short* pw = &pbuf[wave][0][0];

    for (int j = j0; j < j1; j += JT) {
        // ---- stage K tile (64x128) and Vt tile (128x64), 16B per lane ----
#pragma unroll
        for (int p = 0; p < 4; ++p) {
            int slot = p * 256 + t;
            int row = slot >> 4, seg = slot & 15;
            *reinterpret_cast<uint4*>(&kbuf[row][seg * 8]) =
                *reinterpret_cast<const uint4*>(&K[(size_t)(j + row) * DIM + seg * 8]);
        }
#pragma unroll
        for (int p = 0; p < 4; ++p) {
            int slot = p * 256 + t;
            int row = slot >> 3, seg = slot & 7;
            *reinterpret_cast<uint4*>(&vbuf[row][seg * 8]) =
                *reinterpret_cast<const uint4*>(&Vt[(size_t)row * N_TOK + j + seg * 8]);
        }
        if (t < JT) {
            int i = j + t;
            ubuf[t] = (int)(i64 ? u32[2 * i] : u32[i]);
        }
        __syncthreads();

        // ---- S = Q @ K^T (2 x 16 rows x 64 cols per wave) ----
        f32x4 s[2][4];
#pragma unroll
        for (int mt = 0; mt < 2; ++mt)
#pragma unroll
            for (int nt = 0; nt < 4; ++nt) s[mt][nt] = f32x4{0.f, 0.f, 0.f, 0.f};
#pragma unroll
        for (int nt = 0; nt < 4; ++nt)
#pragma unroll
            for (int ks = 0; ks < 4; ++ks) {
                bf16x8 b = *reinterpret_cast<const bf16x8*>(&kbuf[nt * 16 + ln][ks * 32 + q8]);
                s[0][nt] = __builtin_amdgcn_mfma_f32_16x16x32_bf16(qf[0][ks], b, s[0][nt], 0, 0, 0);
                s[1][nt] = __builtin_amdgcn_mfma_f32_16x16x32_bf16(qf[1][ks], b, s[1][nt], 0, 0, 0);
            }

        int uk[4];
#pragma unroll
        for (int nt = 0; nt < 4; ++nt) uk[nt] = ubuf[nt * 16 + ln];

        // ---- fixed-offset softmax: p = exp2(s*lscale + (same?cbias:cnob)) ----
#pragma unroll
        for (int mt = 0; mt < 2; ++mt)
#pragma unroll
            for (int r = 0; r < 4; ++r) {
#pragma unroll
                for (int nt = 0; nt < 4; ++nt) {
                    float v = s[mt][nt][r] * lscale + (uq[mt][r] == uk[nt] ? cbias : cnob);
                    float p = exp2f(v);
                    lsum[mt][r] += p;
                    pw[(mt * 16 + quad * 4 + r) * PP + nt * 16 + ln] = f2b(p);
                }
            }

        __syncthreads();   // P writes visible (and kbuf reads done)

        // ---- O += P @ V ----
        bf16x8 pa[2][2];
#pragma unroll
        for (int mt = 0; mt < 2; ++mt)
#pragma unroll
            for (int k2 = 0; k2 < 2; ++k2)
                pa[mt][k2] = *reinterpret_cast<const bf16x8*>(&pw[(mt * 16 + ln) * PP + k2 * 32 + q8]);
#pragma unroll
        for (int dt = 0; dt < 8; ++dt)
#pragma unroll
            for (int k2 = 0; k2 < 2; ++k2) {
                bf16x8 b = *reinterpret_cast<const bf16x8*>(&vbuf[dt * 16 + ln][k2 * 32 + q8]);
                o[0][dt] = __builtin_amdgcn_mfma_f32_16x16x32_bf16(pa[0][k2], b, o[0][dt], 0, 0, 0);
                o[1][dt] = __builtin_amdgcn_mfma_f32_16x16x32_bf16(pa[1][k2], b, o[1][dt], 0, 0, 0);
            }
        __syncthreads();   // protect kbuf/vbuf/pbuf before next staging
    }

    // ---- epilogue: reduce l across the 16 lanes of each row ----
#pragma unroll
    for (int mt = 0; mt < 2; ++mt)
#pragma unroll
        for (int r = 0; r < 4; ++r) {
            float l = lsum[mt][r];
            l += __shfl_xor(l, 1, 64);
            l += __shfl_xor(l, 2, 64);
            l += __shfl_xor(l, 4, 64);
            l += __shfl_xor(l, 8, 64);
            lsum[mt][r] = l;
        }

    if (out != nullptr) {
        // direct: normalize, canary, store fp32
#pragma unroll
        for (int mt = 0; mt < 2; ++mt)
#pragma unroll
            for (int r = 0; r < 4; ++r) {
                float l = lsum[mt][r];
                bool lbad = !(l > 0.f) || !(l < 3.0e38f);
                float inv = 1.0f / l;
                int row = r0 + mt * 16 + quad * 4 + r;
#pragma unroll
                for (int dt = 0; dt < 8; ++dt) {
                    float v = o[mt][dt][r] * inv;
                    if (v != v) v = 12345.0f;
                    if (lbad)   v = 23456.0f;
                    out[(size_t)row * DIM + dt * 16 + ln] = v;
                }
            }
    } else {
        // split: write unnormalized partial O and partial l (merge = plain sum)
        const size_t base = (size_t)split * N_TOK;
#pragma unroll
        for (int mt = 0; mt < 2; ++mt) {
#pragma unroll
            for (int r = 0; r < 4; ++r) {
                int row = r0 + mt * 16 + quad * 4 + r;
#pragma unroll
                for (int dt = 0; dt < 8; ++dt)
                    pO[(base + row) * DIM + dt * 16 + ln] = o[mt][dt][r];
                if (ln == 0)
                    pl[base + row] = lsum[mt][r];
            }
        }
    }
}

// ---------------------------------------------------------------------------
// Merge: out[row] = (sum_s pO[s][row]) / (sum_s pl[s][row]).
// block 256 = 4 waves = 4 rows; lane covers 2 cols (float2). grid N/4.
// ---------------------------------------------------------------------------
__global__ __launch_bounds__(256)
void merge_kernel(const float* __restrict__ pO, const float* __restrict__ pl,
                  float* __restrict__ out, int ns)
{
    const int t = threadIdx.x;
    const int wave = t >> 6, lane = t & 63;
    const int row = blockIdx.x * 4 + wave;
    const int c = lane * 2;

    float l = 0.f;
    for (int s = 0; s < ns; ++s) l += pl[(size_t)s * N_TOK + row];
    bool lbad = !(l > 0.f) || !(l < 3.0e38f);
    float inv = 1.0f / l;

    float a0 = 0.f, a1 = 0.f;
    for (int s = 0; s < ns; ++s) {
        const float2 v = *reinterpret_cast<const float2*>(
            &pO[((size_t)s * N_TOK + row) * DIM + c]);
        a0 += v.x; a1 += v.y;
    }
    float v0 = a0 * inv, v1 = a1 * inv;
    if (v0 != v0) v0 = 12345.0f;
    if (v1 != v1) v1 = 12345.0f;
    if (lbad) { v0 = 23456.0f; v1 = 23456.0f; }
    float2 res; res.x = v0; res.y = v1;
    *reinterpret_cast<float2*>(&out[(size_t)row * DIM + c]) = res;
}

// ---------------------------------------------------------------------------
extern "C" void kernel_launch(void* const* d_in, const int* in_sizes, int n_in,
                              void* d_out, int out_size, void* d_ws, size_t ws_size,
                              hipStream_t stream)
{
    float* out = (float*)d_out;

    // Shape sanity: signature 5555 if the problem isn't what we assume.
    bool ok = (n_in == 5) &&
              in_sizes[0] == N_TOK * DIM && in_sizes[1] == N_TOK &&
              in_sizes[2] == DIM * DIM && in_sizes[3] == DIM * DIM &&
              in_sizes[4] == DIM * DIM && out_size == N_TOK * DIM;
    if (!ok) { marker_kernel<<<8192, 256, 0, stream>>>(out, 5555.f); return; }

    const float*        xf  = (const float*)d_in[0];
    const unsigned int* u32 = (const unsigned int*)d_in[1];
    const float*        wqf = (const float*)d_in[2];
    const float*        wkf = (const float*)d_in[3];
    const float*        wvf = (const float*)d_in[4];

    char* ws = (char*)d_ws;
    size_t off = 0;
    unsigned short* Q  = (unsigned short*)(ws + off); off += (size_t)N_TOK * DIM * 2;  // 4 MB
    unsigned short* K  = (unsigned short*)(ws + off); off += (size_t)N_TOK * DIM * 2;  // 4 MB
    unsigned short* Vt = (unsigned short*)(ws + off); off += (size_t)N_TOK * DIM * 2;  // 4 MB

    // Workspace sanity: signature 4444 if ws can't hold Q/K/Vt.
    if (ws_size < off) { marker_kernel<<<8192, 256, 0, stream>>>(out, 4444.f); return; }

    // Split-count selection: largest nsplit whose fp32 partials fit in ws.
    const size_t per_split = (size_t)N_TOK * DIM * 4 + (size_t)N_TOK * 4;
    int nsplit = 1;
    if (ws_size >= off + 4 * per_split)      nsplit = 4;
    else if (ws_size >= off + 2 * per_split) nsplit = 2;

    qkv_kernel<<<dim3(N_TOK / 64, 3), 256, 0, stream>>>(xf, wqf, wkf, wvf, Q, K, Vt);

    if (nsplit >= 2) {
        float* pO = (float*)(ws + off);
        float* pl = (float*)(ws + off + (size_t)nsplit * N_TOK * DIM * 4);
        flash_kernel<<<dim3(N_TOK / 128, nsplit), 256, 0, stream>>>(
            Q, K, Vt, u32, N_TOK / nsplit, pO, pl, nullptr);
        merge_kernel<<<N_TOK / 4, 256, 0, stream>>>(pO, pl, out, nsplit);
    } else {
        flash_kernel<<<dim3(N_TOK / 128, 1), 256, 0, stream>>>(
            Q, K, Vt, u32, N_TOK, nullptr, nullptr, out);
    }
}